// Round 8
// baseline (243.523 us; speedup 1.0000x reference)
//
#include <hip/hip_runtime.h>
#include <math.h>

typedef __bf16 bf16_t;
typedef bf16_t bf16x8 __attribute__((ext_vector_type(8)));
typedef bf16_t bf16x4 __attribute__((ext_vector_type(4)));
typedef float  f32x4  __attribute__((ext_vector_type(4)));
typedef int    intx4  __attribute__((ext_vector_type(4)));

#define MFMA16(a, b, c) __builtin_amdgcn_mfma_f32_16x16x32_bf16(a, b, c, 0, 0, 0)
#define NTL(p) __builtin_nontemporal_load((const intx4*)(p))

// lgkmcnt(0) ONLY (vmcnt untouched) -- see R6.
#define LGKM0_ONLY() do {                         \
    __builtin_amdgcn_sched_barrier(0);            \
    __builtin_amdgcn_s_waitcnt(0xC07F);           \
    __builtin_amdgcn_sched_barrier(0);            \
} while (0)

__device__ __forceinline__ float bpermf(int byteidx, float v) {
    return __int_as_float(__builtin_amdgcn_ds_bpermute(byteidx, __float_as_int(v)));
}

constexpr float BN_INV = 0.999995000037499687f;  // 1/sqrt(1+1e-5)

// ---------------------------------------------------------------------------
// K1: f = ReLU(BN(W2 @ feature)) -> bf16 table fbf[t][32] (64B rows) and
// xyz4 float4 table (R6 layout; fp8 packing reverted -- failed accuracy).
// ---------------------------------------------------------------------------
__global__ __launch_bounds__(256) void rfa_k1(
    const float* __restrict__ feature, const float* __restrict__ xyz,
    const float* __restrict__ W2,
    const float* __restrict__ g2, const float* __restrict__ b2,
    bf16_t* __restrict__ fbf, float4* __restrict__ xyz4,
    int N, int nwaves)
{
    int gtid = blockIdx.x * 256 + threadIdx.x;
    int w = gtid >> 6, lane = gtid & 63;
    if (w >= nwaves) return;
    int pt = lane & 15, quad = lane >> 4;
    int T0 = w * 64;
    int b  = T0 / N;
    int n0 = T0 - b * N;

    {
        size_t p = (size_t)T0 + lane;
        xyz4[p] = make_float4(xyz[p * 3], xyz[p * 3 + 1], xyz[p * 3 + 2], 0.f);
    }

    bf16x8 A[2][2];
    #pragma unroll
    for (int mt = 0; mt < 2; ++mt) {
        int h = mt * 16 + pt;
        float sc = g2[h] * BN_INV;
        #pragma unroll
        for (int ks = 0; ks < 2; ++ks) {
            const float* src = W2 + h * 64 + ks * 32 + quad * 8;
            bf16x8 v;
            #pragma unroll
            for (int j = 0; j < 8; ++j) v[j] = (bf16_t)(src[j] * sc);
            A[mt][ks] = v;
        }
    }
    float b2r[8];
    #pragma unroll
    for (int mt = 0; mt < 2; ++mt)
        #pragma unroll
        for (int r = 0; r < 4; ++r) b2r[mt * 4 + r] = b2[mt * 16 + quad * 4 + r];

    const float* fb = feature + (size_t)b * 64 * N;

    #pragma unroll
    for (int g = 0; g < 4; ++g) {
        int nn = n0 + g * 16 + pt;
        size_t T = (size_t)T0 + g * 16 + pt;
        bf16x8 Bf[2];
        #pragma unroll
        for (int ks = 0; ks < 2; ++ks) {
            bf16x8 v;
            #pragma unroll
            for (int j = 0; j < 8; ++j)
                v[j] = (bf16_t)fb[(size_t)(ks * 32 + quad * 8 + j) * N + nn];
            Bf[ks] = v;
        }
        f32x4 acc[2] = {f32x4{0,0,0,0}, f32x4{0,0,0,0}};
        #pragma unroll
        for (int mt = 0; mt < 2; ++mt) {
            acc[mt] = MFMA16(A[mt][0], Bf[0], acc[mt]);
            acc[mt] = MFMA16(A[mt][1], Bf[1], acc[mt]);
        }
        #pragma unroll
        for (int mt = 0; mt < 2; ++mt) {
            bf16x4 o;
            #pragma unroll
            for (int r = 0; r < 4; ++r)
                o[r] = (bf16_t)fmaxf(acc[mt][r] + b2r[mt * 4 + r], 0.f);
            *(bf16x4*)(fbf + T * 32 + mt * 16 + quad * 4) = o;
        }
    }
}

// ---------------------------------------------------------------------------
// K2: R3-R6 pinned at 65-68us under every scheduling change. Accounting:
// ~136K vector-memory LANE-REQUESTS per CU over 158K cycles = 0.86 req/cy --
// the CU address path (TA/TCP, ~1 scattered lane-request/cy) is the saturated
// pipe. Latency-hiding can't help a saturated pipe; only REQUEST COUNT can.
// THIS REV (-44% lane-requests, zero precision change):
//  1. xyz gathers: all 4 quads loaded IDENTICAL float4 -> mask load to
//     quad==0 (masked lanes issue no transactions), broadcast x/y/z via
//     ds_bpermute (LDS pipe, off the TA path). 1024->256 req/group.
//  2. stores: 16 scalar dwords -> LDS transpose bounce -> 4x dwordx4.
//     1024->256 req/group.
//  3. self-xyz ps/psN loads masked the same way.
// ---------------------------------------------------------------------------
__global__ __launch_bounds__(256) void rfa_k2(
    const bf16_t* __restrict__ fbf, const float4* __restrict__ xyz4,
    const int* __restrict__ nidx,
    const float* __restrict__ W1, const float* __restrict__ g1, const float* __restrict__ b1,
    const float* __restrict__ W3, const float* __restrict__ g3, const float* __restrict__ b3,
    const float* __restrict__ W4, const float* __restrict__ g4, const float* __restrict__ b4,
    float* __restrict__ out, int N)
{
    __shared__ __align__(16) bf16_t sW4[8 * 64 * 8];  // staged W4 A-frags (8KB)
    __shared__ float sB[4][32 * 18];                   // per-wave bounce [ch][pt] (9KB)
    __shared__ __align__(16) float sOut[4][64 * 20];   // per-wave out transpose (20.5KB)
    __shared__ __align__(16) float sb34[96];           // b3 (0..31), b4 (32..95)

    int tid = threadIdx.x;
    for (int s = tid; s < 512; s += 256) {
        int f = s >> 6, l = s & 63;
        int mt = f >> 1, ks = f & 1, nn = l & 15, q = l >> 4;
        int o = mt * 16 + nn;
        float sc = g4[o] * BN_INV;
        const float* src = W4 + o * 64 + ks * 32 + q * 8;
        bf16x8 v;
        #pragma unroll
        for (int j = 0; j < 8; ++j) v[j] = (bf16_t)(src[j] * sc);
        *(bf16x8*)(sW4 + s * 8) = v;
    }
    if (tid < 32) sb34[tid] = b3[tid];
    else if (tid < 96) sb34[tid] = b4[tid - 32];
    __syncthreads();

    int lane = tid & 63, wv = tid >> 6;
    int n = lane & 15, quad = lane >> 4;
    int bidx = n * 4;                             // ds_bpermute byte index -> lane n

    // batch->XCD affinity decode: blk%8 ~ XCD, batch b = XCD/2.
    int blk   = blockIdx.x;
    int b     = (blk & 7) >> 1;                   // batch = XCD/2
    int slot  = (blk >> 3) * 2 + (blk & 1);       // per-batch block slot [0,BPB)
    int BPB   = gridDim.x >> 2;                   // blocks per batch (256)
    int WPB   = BPB * 4;                          // waves per batch (1024)
    int wslot = wv * BPB + slot;
    int GPB   = N >> 4;                           // groups per batch (2560)
    int base  = b * N;

    // W3 A-frags (g3-folded), persistent
    bf16x8 A3[2][2];
    #pragma unroll
    for (int mt = 0; mt < 2; ++mt) {
        int h = mt * 16 + n;
        float sc = g3[h] * BN_INV;
        #pragma unroll
        for (int ks = 0; ks < 2; ++ks) {
            const float* src = W3 + h * 64 + ks * 32 + quad * 8;
            bf16x8 v;
            #pragma unroll
            for (int j = 0; j < 8; ++j) v[j] = (bf16_t)(src[j] * sc);
            A3[mt][ks] = v;
        }
    }
    // W1 algebra (channels c = quad*8+j)
    float a8[8], V0[8], V1[8], V2[8];
    #pragma unroll
    for (int j = 0; j < 8; ++j) {
        int c = quad * 8 + j;
        float s1 = g1[c] * BN_INV;
        const float* wp = W1 + c * 10;
        a8[j] = wp[0] * s1;
        V0[j] = (wp[7] - wp[1]) * s1;
        V1[j] = (wp[8] - wp[2]) * s1;
        V2[j] = (wp[9] - wp[3]) * s1;
    }

    const bf16_t* fb  = fbf  + (size_t)base * 32;
    const float4* xzb = xyz4 + (size_t)base;
    float* bounce = sB[wv];
    float* obuf   = sOut[wv];

    // ---- prime the cross-group pipeline for the first group ----
    size_t tg = (size_t)base + (size_t)wslot * 16 + n;
    const int* nb = nidx + tg * 16;
    intx4 c1, c2;                                 // j4..7 / j8..11 of CURRENT group
    float4 ps;                                    // self xyz (valid in quad0 only)
    bf16x8 fj[4]; float4 pn[4];                   // depth-4 gather slots
    {
        intx4 c0 = NTL(nb + 0);                   // j0..j3
        c1 = NTL(nb + 4);
        if (quad == 0) ps = xyz4[tg];
        #pragma unroll
        for (int s = 0; s < 4; ++s) {
            int j0 = c0[s];
            fj[s] = *(const bf16x8*)(fb + (size_t)j0 * 32 + quad * 8);
            if (quad == 0) pn[s] = xzb[j0];       // masked: no TA work in quads 1-3
        }
        c2 = NTL(nb + 8);
    }

    for (int grp = wslot; grp < GPB; grp += WPB) {
        int  nloc = grp * 16;
        bool hn   = (grp + WPB) < GPB;
        size_t tgN = hn ? tg + (size_t)WPB * 16 : tg;
        const int* nbN = nidx + tgN * 16;

        // broadcast self xyz (quad0 -> all quads) once per group
        float psx = bpermf(bidx, ps.x);
        float psy = bpermf(bidx, ps.y);
        float psz = bpermf(bidx, ps.z);

        float hoist[8];
        #pragma unroll
        for (int j = 0; j < 8; ++j) {
            int c = quad * 8 + j;
            float s1 = g1[c] * BN_INV;
            const float* wp = W1 + c * 10;
            hoist[j] = b1[c] + ((wp[1] + wp[4]) * psx + (wp[2] + wp[5]) * psy +
                                (wp[3] + wp[6]) * psz) * s1;
        }

        f32x4 mx0 = {-3.0e38f, -3.0e38f, -3.0e38f, -3.0e38f};
        f32x4 mx1 = {-3.0e38f, -3.0e38f, -3.0e38f, -3.0e38f};
        intx4 c3, cA;                             // j12..15 / NEXT group's j0..3
        float4 psN;

        #pragma unroll
        for (int k = 0; k < 16; ++k) {
            int s = k & 3;
            // broadcast neighbor xyz (loaded by quad0 >=4 iters ago)
            float pnx = bpermf(bidx, pn[s].x);
            float pny = bpermf(bidx, pn[s].y);
            float pnz = bpermf(bidx, pn[s].z);
            bf16x8 Bj = fj[s];

            float rx = psx - pnx, ry = psy - pny, rz = psz - pnz;
            float dist = __builtin_amdgcn_sqrtf(rx * rx + ry * ry + rz * rz);

            bf16x8 Bx;
            #pragma unroll
            for (int c = 0; c < 8; ++c) {
                float v = fmaf(a8[c], dist, hoist[c]);
                v = fmaf(V0[c], pnx, v);
                v = fmaf(V1[c], pny, v);
                v = fmaf(V2[c], pnz, v);
                Bx[c] = (bf16_t)fmaxf(v, 0.f);
            }

            f32x4 ac0 = {0,0,0,0}, ac1 = {0,0,0,0};
            ac0 = MFMA16(A3[0][0], Bj, ac0);
            ac0 = MFMA16(A3[0][1], Bx, ac0);
            ac1 = MFMA16(A3[1][0], Bj, ac1);
            ac1 = MFMA16(A3[1][1], Bx, ac1);
            #pragma unroll
            for (int r = 0; r < 4; ++r) {
                mx0[r] = fmaxf(mx0[r], ac0[r]);
                mx1[r] = fmaxf(mx1[r], ac1[r]);
            }

            // refill slot s: k<12 -> this group's j(k+4); k>=12 -> NEXT group's
            {
                int jn;
                if      (k < 4)  jn = c1[k];
                else if (k < 8)  jn = c2[k - 4];
                else if (k < 12) jn = c3[k - 8];
                else             jn = cA[k - 12];
                fj[s] = *(const bf16x8*)(fb + (size_t)jn * 32 + quad * 8);
                if (quad == 0) pn[s] = xzb[jn];
            }
            // chunk/self prefetch schedule (targets are dead registers):
            if (k == 2)  c3 = NTL(nb + 12);
            if (k == 4)  cA = NTL(nbN + 0);
            if (k == 8)  c1 = NTL(nbN + 4);
            if (k == 12) { if (quad == 0) psN = xyz4[tgN]; }
            if (k == 13) c2 = NTL(nbN + 8);
        }

        // epilogue: bias+ReLU on max, bounce to B-layout, W4 MFMA
        f32x4 bz0 = *(const f32x4*)&sb34[quad * 4];
        f32x4 bz1 = *(const f32x4*)&sb34[16 + quad * 4];
        #pragma unroll
        for (int r = 0; r < 4; ++r) {
            bounce[(quad * 4 + r) * 18 + n]      = fmaxf(mx0[r] + bz0[r], 0.f);
            bounce[(16 + quad * 4 + r) * 18 + n] = fmaxf(mx1[r] + bz1[r], 0.f);
        }
        LGKM0_ONLY();   // lgkmcnt(0) only -- vmcnt pipeline stays in flight
        bf16x8 Bm;
        #pragma unroll
        for (int jj = 0; jj < 8; ++jj)
            Bm[jj] = (bf16_t)bounce[(quad * 8 + jj) * 18 + n];

        bf16x8 Bs = *(const bf16x8*)(fb + (size_t)(nloc + n) * 32 + quad * 8);  // f_self

        #pragma unroll
        for (int mt = 0; mt < 4; ++mt) {
            bf16x8 A40 = *(const bf16x8*)(sW4 + ((size_t)(mt * 2 + 0) * 64 + lane) * 8);
            bf16x8 A41 = *(const bf16x8*)(sW4 + ((size_t)(mt * 2 + 1) * 64 + lane) * 8);
            f32x4 b4q = *(const f32x4*)&sb34[32 + mt * 16 + quad * 4];
            f32x4 acc = {0,0,0,0};
            acc = MFMA16(A40, Bm, acc);
            acc = MFMA16(A41, Bs, acc);
            #pragma unroll
            for (int r = 0; r < 4; ++r) {
                int o = mt * 16 + quad * 4 + r;
                obuf[o * 20 + n] = fmaxf(acc[r] + b4q[r], 0.f);  // LDS transpose
            }
        }
        LGKM0_ONLY();
        // transposed store: 4x dwordx4 per lane (256 lane-requests vs 1024)
        #pragma unroll
        for (int i = 0; i < 4; ++i) {
            int o = i * 16 + (lane >> 2);
            f32x4 v4 = *(const f32x4*)&obuf[o * 20 + (lane & 3) * 4];
            __builtin_nontemporal_store(
                v4, (f32x4*)&out[((size_t)b * 64 + o) * N + nloc + (lane & 3) * 4]);
        }

        // rotate cross-group pipeline state
        tg = tgN; nb = nbN; ps = psN;
    }
}

// ---------------------------------------------------------------------------
extern "C" void kernel_launch(void* const* d_in, const int* in_sizes, int n_in,
                              void* d_out, int out_size, void* d_ws, size_t ws_size,
                              hipStream_t stream) {
    const float* feature = (const float*)d_in[0];
    const float* xyz     = (const float*)d_in[1];
    const int*   nidx    = (const int*)  d_in[2];
    const float* W1      = (const float*)d_in[3];
    const float* W2      = (const float*)d_in[4];
    const float* W3      = (const float*)d_in[5];
    const float* W4      = (const float*)d_in[6];
    const float* g1 = (const float*)d_in[7];
    const float* b1 = (const float*)d_in[8];
    const float* g2 = (const float*)d_in[9];
    const float* b2 = (const float*)d_in[10];
    const float* g3 = (const float*)d_in[11];
    const float* b3 = (const float*)d_in[12];
    const float* g4 = (const float*)d_in[13];
    const float* b4 = (const float*)d_in[14];
    float* out = (float*)d_out;

    const int B = 4;
    const int N = in_sizes[1] / (B * 3);
    const int total = B * N;                      // 163840

    bf16_t* fbf  = (bf16_t*)d_ws;                 // [total][32] bf16  (10.5 MB)
    float4* xyz4 = (float4*)((char*)d_ws + (size_t)total * 32 * sizeof(bf16_t));

    const int nw1 = total / 64;
    const int blk1 = (nw1 + 3) / 4;
    const int blk2 = 1024;

    rfa_k1<<<blk1, 256, 0, stream>>>(feature, xyz, W2, g2, b2, fbf, xyz4, N, nw1);
    rfa_k2<<<blk2, 256, 0, stream>>>(fbf, xyz4, nidx, W1, g1, b1, W3, g3, b3,
                                     W4, g4, b4, out, N);
}

// Round 9
// 208.642 us; speedup vs baseline: 1.1672x; 1.1672x over previous
//
#include <hip/hip_runtime.h>
#include <math.h>

typedef __bf16 bf16_t;
typedef bf16_t bf16x8 __attribute__((ext_vector_type(8)));
typedef bf16_t bf16x4 __attribute__((ext_vector_type(4)));
typedef float  f32x4  __attribute__((ext_vector_type(4)));
typedef int    intx4  __attribute__((ext_vector_type(4)));

#define MFMA16(a, b, c) __builtin_amdgcn_mfma_f32_16x16x32_bf16(a, b, c, 0, 0, 0)

constexpr float BN_INV = 0.999995000037499687f;  // 1/sqrt(1+1e-5)

// ---------------------------------------------------------------------------
// K1: f = ReLU(BN(W2 @ feature)) -> bf16 table fbf[t][32] (64B rows) and
// xyz4 float4 table. Unchanged (isolating the k2 occupancy experiment).
// ---------------------------------------------------------------------------
__global__ __launch_bounds__(256) void rfa_k1(
    const float* __restrict__ feature, const float* __restrict__ xyz,
    const float* __restrict__ W2,
    const float* __restrict__ g2, const float* __restrict__ b2,
    bf16_t* __restrict__ fbf, float4* __restrict__ xyz4,
    int N, int nwaves)
{
    int gtid = blockIdx.x * 256 + threadIdx.x;
    int w = gtid >> 6, lane = gtid & 63;
    if (w >= nwaves) return;
    int pt = lane & 15, quad = lane >> 4;
    int T0 = w * 64;
    int b  = T0 / N;
    int n0 = T0 - b * N;

    {
        size_t p = (size_t)T0 + lane;
        xyz4[p] = make_float4(xyz[p * 3], xyz[p * 3 + 1], xyz[p * 3 + 2], 0.f);
    }

    bf16x8 A[2][2];
    #pragma unroll
    for (int mt = 0; mt < 2; ++mt) {
        int h = mt * 16 + pt;
        float sc = g2[h] * BN_INV;
        #pragma unroll
        for (int ks = 0; ks < 2; ++ks) {
            const float* src = W2 + h * 64 + ks * 32 + quad * 8;
            bf16x8 v;
            #pragma unroll
            for (int j = 0; j < 8; ++j) v[j] = (bf16_t)(src[j] * sc);
            A[mt][ks] = v;
        }
    }
    float b2r[8];
    #pragma unroll
    for (int mt = 0; mt < 2; ++mt)
        #pragma unroll
        for (int r = 0; r < 4; ++r) b2r[mt * 4 + r] = b2[mt * 16 + quad * 4 + r];

    const float* fb = feature + (size_t)b * 64 * N;

    #pragma unroll
    for (int g = 0; g < 4; ++g) {
        int nn = n0 + g * 16 + pt;
        size_t T = (size_t)T0 + g * 16 + pt;
        bf16x8 Bf[2];
        #pragma unroll
        for (int ks = 0; ks < 2; ++ks) {
            bf16x8 v;
            #pragma unroll
            for (int j = 0; j < 8; ++j)
                v[j] = (bf16_t)fb[(size_t)(ks * 32 + quad * 8 + j) * N + nn];
            Bf[ks] = v;
        }
        f32x4 acc[2] = {f32x4{0,0,0,0}, f32x4{0,0,0,0}};
        #pragma unroll
        for (int mt = 0; mt < 2; ++mt) {
            acc[mt] = MFMA16(A[mt][0], Bf[0], acc[mt]);
            acc[mt] = MFMA16(A[mt][1], Bf[1], acc[mt]);
        }
        #pragma unroll
        for (int mt = 0; mt < 2; ++mt) {
            bf16x4 o;
            #pragma unroll
            for (int r = 0; r < 4; ++r)
                o[r] = (bf16_t)fmaxf(acc[mt][r] + b2r[mt * 4 + r], 0.f);
            *(bf16x4*)(fbf + T * 32 + mt * 16 + quad * 4) = o;
        }
    }
}

// ---------------------------------------------------------------------------
// K2: R8 accidentally ran the occupancy experiment: 2 waves/SIMD (VGPR 216)
// -> 128us vs 4 waves -> 66us. Time scales ~1/waves => per-wave-latency
// bound; only MORE resident waves help. R1 proved launch_bounds coercion
// spills; THIS REV sheds 32 live VGPRs for real: the W1 coefficient arrays
// (a8/V0/V1/V2, live across the whole 16-iter loop) move to block-shared LDS
// (sV, 512B) and are re-read per iteration as VOLATILE f32x4 slices
// (volatile defeats unroll-CSE re-hoisting). Same-address-per-quad =>
// LDS broadcast, conflict-free, compile-time offsets, zero extra VALU.
// Body reverted to the proven R3/R4 depth-4 structure. Grid 1280 = 5
// blocks/CU co-resident, exactly 2 groups/wave. Target VGPR <= 96.
// ---------------------------------------------------------------------------
__global__ __launch_bounds__(256) void rfa_k2(
    const bf16_t* __restrict__ fbf, const float4* __restrict__ xyz4,
    const int* __restrict__ nidx,
    const float* __restrict__ W1, const float* __restrict__ g1, const float* __restrict__ b1,
    const float* __restrict__ W3, const float* __restrict__ g3, const float* __restrict__ b3,
    const float* __restrict__ W4, const float* __restrict__ g4, const float* __restrict__ b4,
    float* __restrict__ out, int N)
{
    __shared__ __align__(16) bf16_t sW4[8 * 64 * 8];  // staged W4 A-frags (8KB)
    __shared__ float sB[4][32 * 18];                   // per-wave bounce [ch][pt] (9KB)
    __shared__ __align__(16) float sV[128];            // a[32],V0[32],V1[32],V2[32]
    __shared__ __align__(16) float sb34[96];           // b3 (0..31), b4 (32..95)

    int tid = threadIdx.x;
    for (int s = tid; s < 512; s += 256) {
        int f = s >> 6, l = s & 63;
        int mt = f >> 1, ks = f & 1, nn = l & 15, q = l >> 4;
        int o = mt * 16 + nn;
        float sc = g4[o] * BN_INV;
        const float* src = W4 + o * 64 + ks * 32 + q * 8;
        bf16x8 v;
        #pragma unroll
        for (int j = 0; j < 8; ++j) v[j] = (bf16_t)(src[j] * sc);
        *(bf16x8*)(sW4 + s * 8) = v;
    }
    if (tid < 32) {
        int c = tid;
        float s1 = g1[c] * BN_INV;
        const float* wp = W1 + c * 10;
        sV[c]      = wp[0] * s1;                  // a
        sV[32 + c] = (wp[7] - wp[1]) * s1;        // V0
        sV[64 + c] = (wp[8] - wp[2]) * s1;        // V1
        sV[96 + c] = (wp[9] - wp[3]) * s1;        // V2
        sb34[c] = b3[c];
    } else if (tid >= 64 && tid < 128) {
        sb34[tid - 32] = b4[tid - 64];
    }
    __syncthreads();

    int lane = tid & 63, wv = tid >> 6;
    int n = lane & 15, quad = lane >> 4;

    // batch->XCD affinity decode: blk%8 ~ XCD, batch b = XCD/2.
    int blk   = blockIdx.x;
    int b     = (blk & 7) >> 1;                   // batch = XCD/2
    int slot  = (blk >> 3) * 2 + (blk & 1);       // per-batch block slot [0,BPB)
    int BPB   = gridDim.x >> 2;                   // blocks per batch (320)
    int WPB   = BPB * 4;                          // waves per batch (1280)
    int wslot = wv * BPB + slot;
    int GPB   = N >> 4;                           // groups per batch (2560)
    int base  = b * N;

    // W3 A-frags (g3-folded), persistent in registers (MFMA A-operand)
    bf16x8 A3[2][2];
    #pragma unroll
    for (int mt = 0; mt < 2; ++mt) {
        int h = mt * 16 + n;
        float sc = g3[h] * BN_INV;
        #pragma unroll
        for (int ks = 0; ks < 2; ++ks) {
            const float* src = W3 + h * 64 + ks * 32 + quad * 8;
            bf16x8 v;
            #pragma unroll
            for (int j = 0; j < 8; ++j) v[j] = (bf16_t)(src[j] * sc);
            A3[mt][ks] = v;
        }
    }

    const bf16_t* fb  = fbf  + (size_t)base * 32;
    const float4* xzb = xyz4 + (size_t)base;
    float* bounce = sB[wv];
    // volatile views of the coefficient slices: re-read each use, never
    // register-resident across the loop (the whole point of this rev)
    volatile const f32x4* vA  = (volatile const f32x4*)&sV[0  + quad * 8];
    volatile const f32x4* vV0 = (volatile const f32x4*)&sV[32 + quad * 8];
    volatile const f32x4* vV1 = (volatile const f32x4*)&sV[64 + quad * 8];
    volatile const f32x4* vV2 = (volatile const f32x4*)&sV[96 + quad * 8];

    for (int grp = wslot; grp < GPB; grp += WPB) {
        int nloc = grp * 16;
        size_t tg = (size_t)base + nloc + n;      // this lane's column point

        float4 ps = xyz4[tg];                     // self xyz (4-dup across quads)
        float hoist[8];
        #pragma unroll
        for (int j = 0; j < 8; ++j) {
            int c = quad * 8 + j;
            float s1 = g1[c] * BN_INV;
            const float* wp = W1 + c * 10;
            hoist[j] = b1[c] + ((wp[1] + wp[4]) * ps.x + (wp[2] + wp[5]) * ps.y +
                                (wp[3] + wp[6]) * ps.z) * s1;
        }

        // neighbor indices: 2 rotating int4 chunks (plain cached loads)
        const int* nb = nidx + tg * 16;
        intx4 nc0 = *(const intx4*)(nb + 0);      // j0..j3
        intx4 nc1 = *(const intx4*)(nb + 4);      // j4..j7

        // depth-4 pipelined gather: prologue issues 4 pairs (j0..j3)
        bf16x8 fj[4]; float4 pn[4];
        #pragma unroll
        for (int s = 0; s < 4; ++s) {
            int j0 = nc0[s];
            fj[s] = *(const bf16x8*)(fb + (size_t)j0 * 32 + quad * 8);
            pn[s] = xzb[j0];
        }
        nc0 = *(const intx4*)(nb + 8);            // j8..j11 (first use: k==4)

        f32x4 mx0 = {-3.0e38f, -3.0e38f, -3.0e38f, -3.0e38f};
        f32x4 mx1 = {-3.0e38f, -3.0e38f, -3.0e38f, -3.0e38f};

        #pragma unroll
        for (int k = 0; k < 16; ++k) {
            int s = k & 3;
            float4 p = pn[s];
            bf16x8 Bj = fj[s];

            float rx = ps.x - p.x, ry = ps.y - p.y, rz = ps.z - p.z;
            float dist = __builtin_amdgcn_sqrtf(rx * rx + ry * ry + rz * rz);

            bf16x8 Bx;
            #pragma unroll
            for (int hf = 0; hf < 2; ++hf) {
                f32x4 aa = vA[hf];                // 16B broadcast reads (LDS pipe)
                f32x4 w0 = vV0[hf];
                f32x4 w1 = vV1[hf];
                f32x4 w2 = vV2[hf];
                #pragma unroll
                for (int c = 0; c < 4; ++c) {
                    float v = fmaf(aa[c], dist, hoist[hf * 4 + c]);
                    v = fmaf(w0[c], p.x, v);
                    v = fmaf(w1[c], p.y, v);
                    v = fmaf(w2[c], p.z, v);
                    Bx[hf * 4 + c] = (bf16_t)fmaxf(v, 0.f);
                }
            }

            f32x4 ac0 = {0,0,0,0}, ac1 = {0,0,0,0};
            ac0 = MFMA16(A3[0][0], Bj, ac0);
            ac0 = MFMA16(A3[0][1], Bx, ac0);
            ac1 = MFMA16(A3[1][0], Bj, ac1);
            ac1 = MFMA16(A3[1][1], Bx, ac1);
            #pragma unroll
            for (int r = 0; r < 4; ++r) {
                mx0[r] = fmaxf(mx0[r], ac0[r]);
                mx1[r] = fmaxf(mx1[r], ac1[r]);
            }

            if (k + 4 < 16) {
                int t = k + 4;                    // compile-time constant
                int jn;
                if      (t < 8)  jn = nc1[t - 4];    // orig nc1 (k<=3)
                else if (t < 12) jn = nc0[t - 8];    // reloaded nc0 (k=4..7)
                else             jn = nc1[t - 12];   // reloaded nc1 (k=8..11)
                fj[s] = *(const bf16x8*)(fb + (size_t)jn * 32 + quad * 8);
                pn[s] = xzb[jn];
            }
            if (k == 3) nc1 = *(const intx4*)(nb + 12);  // j12..j15 (use k==8)
        }

        // epilogue: bias+ReLU on max, bounce to B-layout, W4 MFMA, store
        f32x4 bz0 = *(const f32x4*)&sb34[quad * 4];
        f32x4 bz1 = *(const f32x4*)&sb34[16 + quad * 4];
        #pragma unroll
        for (int r = 0; r < 4; ++r) {
            bounce[(quad * 4 + r) * 18 + n]      = fmaxf(mx0[r] + bz0[r], 0.f);
            bounce[(16 + quad * 4 + r) * 18 + n] = fmaxf(mx1[r] + bz1[r], 0.f);
        }
        asm volatile("s_waitcnt lgkmcnt(0)" ::: "memory");
        bf16x8 Bm;
        #pragma unroll
        for (int jj = 0; jj < 8; ++jj)
            Bm[jj] = (bf16_t)bounce[(quad * 8 + jj) * 18 + n];

        bf16x8 Bs = *(const bf16x8*)(fb + (size_t)(nloc + n) * 32 + quad * 8);  // f_self

        #pragma unroll
        for (int mt = 0; mt < 4; ++mt) {
            bf16x8 A40 = *(const bf16x8*)(sW4 + ((size_t)(mt * 2 + 0) * 64 + lane) * 8);
            bf16x8 A41 = *(const bf16x8*)(sW4 + ((size_t)(mt * 2 + 1) * 64 + lane) * 8);
            f32x4 b4q = *(const f32x4*)&sb34[32 + mt * 16 + quad * 4];
            f32x4 acc = {0,0,0,0};
            acc = MFMA16(A40, Bm, acc);
            acc = MFMA16(A41, Bs, acc);
            #pragma unroll
            for (int r = 0; r < 4; ++r) {
                int o = mt * 16 + quad * 4 + r;
                float res = fmaxf(acc[r] + b4q[r], 0.f);
                __builtin_nontemporal_store(res, &out[((size_t)b * 64 + o) * N + nloc + n]);
            }
        }
        asm volatile("s_waitcnt lgkmcnt(0)" ::: "memory");  // drain before next group's bounce
    }
}

// ---------------------------------------------------------------------------
extern "C" void kernel_launch(void* const* d_in, const int* in_sizes, int n_in,
                              void* d_out, int out_size, void* d_ws, size_t ws_size,
                              hipStream_t stream) {
    const float* feature = (const float*)d_in[0];
    const float* xyz     = (const float*)d_in[1];
    const int*   nidx    = (const int*)  d_in[2];
    const float* W1      = (const float*)d_in[3];
    const float* W2      = (const float*)d_in[4];
    const float* W3      = (const float*)d_in[5];
    const float* W4      = (const float*)d_in[6];
    const float* g1 = (const float*)d_in[7];
    const float* b1 = (const float*)d_in[8];
    const float* g2 = (const float*)d_in[9];
    const float* b2 = (const float*)d_in[10];
    const float* g3 = (const float*)d_in[11];
    const float* b3 = (const float*)d_in[12];
    const float* g4 = (const float*)d_in[13];
    const float* b4 = (const float*)d_in[14];
    float* out = (float*)d_out;

    const int B = 4;
    const int N = in_sizes[1] / (B * 3);
    const int total = B * N;                      // 163840

    bf16_t* fbf  = (bf16_t*)d_ws;                 // [total][32] bf16  (10.5 MB)
    float4* xyz4 = (float4*)((char*)d_ws + (size_t)total * 32 * sizeof(bf16_t));

    const int nw1 = total / 64;
    const int blk1 = (nw1 + 3) / 4;
    // k2: 1280 blocks = 256 CUs x 5 resident (needs VGPR<=96 -> 5 waves/SIMD;
    // this rev sheds 32 live VGPRs to LDS to get there). Divisible by 8 for
    // the XCD-affinity decode; exactly 2 groups per wave (no tail).
    const int blk2 = 1280;

    rfa_k1<<<blk1, 256, 0, stream>>>(feature, xyz, W2, g2, b2, fbf, xyz4, N, nw1);
    rfa_k2<<<blk2, 256, 0, stream>>>(fbf, xyz4, nidx, W1, g1, b1, W3, g3, b3,
                                     W4, g4, b4, out, N);
}

// Round 10
// 198.547 us; speedup vs baseline: 1.2265x; 1.0508x over previous
//
#include <hip/hip_runtime.h>
#include <math.h>

typedef __bf16 bf16_t;
typedef bf16_t bf16x8 __attribute__((ext_vector_type(8)));
typedef bf16_t bf16x4 __attribute__((ext_vector_type(4)));
typedef float  f32x4  __attribute__((ext_vector_type(4)));
typedef int    intx4  __attribute__((ext_vector_type(4)));
typedef unsigned int uintx4 __attribute__((ext_vector_type(4)));
typedef _Float16 h16;
typedef h16 h16x4 __attribute__((ext_vector_type(4)));

#define MFMA16(a, b, c) __builtin_amdgcn_mfma_f32_16x16x32_bf16(a, b, c, 0, 0, 0)

constexpr float BN_INV = 0.999995000037499687f;  // 1/sqrt(1+1e-5)

// ---------------------------------------------------------------------------
// K1: f = ReLU(BN(W2 @ feature)) -> bf16 table fbf[t][32] (64B rows),
// half4 xyz table xyzh (8B/row -> 1.3MB total, L2-resident), and u16 packed
// neighbor-index table n16 (16 x u16 = 32B/row; indices < 40960 < 2^16).
// ---------------------------------------------------------------------------
__global__ __launch_bounds__(256) void rfa_k1(
    const float* __restrict__ feature, const float* __restrict__ xyz,
    const int* __restrict__ nidx,
    const float* __restrict__ W2,
    const float* __restrict__ g2, const float* __restrict__ b2,
    bf16_t* __restrict__ fbf, h16x4* __restrict__ xyzh,
    unsigned int* __restrict__ n16,
    int N, int nwaves)
{
    int gtid = blockIdx.x * 256 + threadIdx.x;
    int w = gtid >> 6, lane = gtid & 63;
    if (w >= nwaves) return;
    int pt = lane & 15, quad = lane >> 4;
    int T0 = w * 64;
    int b  = T0 / N;
    int n0 = T0 - b * N;

    {
        size_t p = (size_t)T0 + lane;
        h16x4 h; h[0] = (h16)xyz[p * 3]; h[1] = (h16)xyz[p * 3 + 1];
        h[2] = (h16)xyz[p * 3 + 2]; h[3] = (h16)0.f;
        xyzh[p] = h;
        // pack 16 int32 neighbor indices -> 16 u16 (8 uints)
        const int* np_ = nidx + p * 16;
        intx4 a0 = *(const intx4*)(np_ + 0);
        intx4 a1 = *(const intx4*)(np_ + 4);
        intx4 a2 = *(const intx4*)(np_ + 8);
        intx4 a3 = *(const intx4*)(np_ + 12);
        uintx4 w0, w1;
        w0[0] = (unsigned)a0[0] | ((unsigned)a0[1] << 16);
        w0[1] = (unsigned)a0[2] | ((unsigned)a0[3] << 16);
        w0[2] = (unsigned)a1[0] | ((unsigned)a1[1] << 16);
        w0[3] = (unsigned)a1[2] | ((unsigned)a1[3] << 16);
        w1[0] = (unsigned)a2[0] | ((unsigned)a2[1] << 16);
        w1[1] = (unsigned)a2[2] | ((unsigned)a2[3] << 16);
        w1[2] = (unsigned)a3[0] | ((unsigned)a3[1] << 16);
        w1[3] = (unsigned)a3[2] | ((unsigned)a3[3] << 16);
        *(uintx4*)(n16 + p * 8)     = w0;
        *(uintx4*)(n16 + p * 8 + 4) = w1;
    }

    bf16x8 A[2][2];
    #pragma unroll
    for (int mt = 0; mt < 2; ++mt) {
        int h = mt * 16 + pt;
        float sc = g2[h] * BN_INV;
        #pragma unroll
        for (int ks = 0; ks < 2; ++ks) {
            const float* src = W2 + h * 64 + ks * 32 + quad * 8;
            bf16x8 v;
            #pragma unroll
            for (int j = 0; j < 8; ++j) v[j] = (bf16_t)(src[j] * sc);
            A[mt][ks] = v;
        }
    }
    float b2r[8];
    #pragma unroll
    for (int mt = 0; mt < 2; ++mt)
        #pragma unroll
        for (int r = 0; r < 4; ++r) b2r[mt * 4 + r] = b2[mt * 16 + quad * 4 + r];

    const float* fb = feature + (size_t)b * 64 * N;

    #pragma unroll
    for (int g = 0; g < 4; ++g) {
        int nn = n0 + g * 16 + pt;
        size_t T = (size_t)T0 + g * 16 + pt;
        bf16x8 Bf[2];
        #pragma unroll
        for (int ks = 0; ks < 2; ++ks) {
            bf16x8 v;
            #pragma unroll
            for (int j = 0; j < 8; ++j)
                v[j] = (bf16_t)fb[(size_t)(ks * 32 + quad * 8 + j) * N + nn];
            Bf[ks] = v;
        }
        f32x4 acc[2] = {f32x4{0,0,0,0}, f32x4{0,0,0,0}};
        #pragma unroll
        for (int mt = 0; mt < 2; ++mt) {
            acc[mt] = MFMA16(A[mt][0], Bf[0], acc[mt]);
            acc[mt] = MFMA16(A[mt][1], Bf[1], acc[mt]);
        }
        #pragma unroll
        for (int mt = 0; mt < 2; ++mt) {
            bf16x4 o;
            #pragma unroll
            for (int r = 0; r < 4; ++r)
                o[r] = (bf16_t)fmaxf(acc[mt][r] + b2r[mt * 4 + r], 0.f);
            *(bf16x4*)(fbf + T * 32 + mt * 16 + quad * 4) = o;
        }
    }
}

// ---------------------------------------------------------------------------
// K2: R8 proved time ~ 1/resident-waves (2 waves=128us, 4=66us); R1/R9
// proved the register count can't be faked down. THIS REV removes live state
// for real: pn[] as half4 (16->8 VGPR), ps half4 (4->2), ALL 16 u16 indices
// resident in 8 VGPR (no mid-loop chunk reloads), 32-bit table offsets
// (uniform bases stay in SGPR). Target peak <= 102 VGPR -> 5 waves/SIMD.
// Grid 1280 = 5 blocks/CU co-resident, exactly 2 groups/wave. Body is the
// proven R4 depth-4 structure otherwise.
// ---------------------------------------------------------------------------
__global__ __launch_bounds__(256) void rfa_k2(
    const bf16_t* __restrict__ fbf, const h16x4* __restrict__ xyzh,
    const unsigned int* __restrict__ n16,
    const float* __restrict__ W1, const float* __restrict__ g1, const float* __restrict__ b1,
    const float* __restrict__ W3, const float* __restrict__ g3, const float* __restrict__ b3,
    const float* __restrict__ W4, const float* __restrict__ g4, const float* __restrict__ b4,
    float* __restrict__ out, int N)
{
    __shared__ __align__(16) bf16_t sW4[8 * 64 * 8];  // staged W4 A-frags (8KB)
    __shared__ float sB[4][32 * 18];                   // per-wave bounce [ch][pt] (9KB)
    __shared__ __align__(16) float sb34[96];           // b3 (0..31), b4 (32..95)

    int tid = threadIdx.x;
    for (int s = tid; s < 512; s += 256) {
        int f = s >> 6, l = s & 63;
        int mt = f >> 1, ks = f & 1, nn = l & 15, q = l >> 4;
        int o = mt * 16 + nn;
        float sc = g4[o] * BN_INV;
        const float* src = W4 + o * 64 + ks * 32 + q * 8;
        bf16x8 v;
        #pragma unroll
        for (int j = 0; j < 8; ++j) v[j] = (bf16_t)(src[j] * sc);
        *(bf16x8*)(sW4 + s * 8) = v;
    }
    if (tid < 32) sb34[tid] = b3[tid];
    else if (tid < 96) sb34[tid] = b4[tid - 32];
    __syncthreads();

    int lane = tid & 63, wv = tid >> 6;
    int n = lane & 15, quad = lane >> 4;

    // batch->XCD affinity decode: blk%8 ~ XCD, batch b = XCD/2.
    int blk   = blockIdx.x;
    int b     = (blk & 7) >> 1;                   // batch = XCD/2
    int slot  = (blk >> 3) * 2 + (blk & 1);       // per-batch block slot [0,BPB)
    int BPB   = gridDim.x >> 2;                   // blocks per batch (320)
    int WPB   = BPB * 4;                          // waves per batch (1280)
    int wslot = wv * BPB + slot;
    int GPB   = N >> 4;                           // groups per batch (2560)
    int base  = b * N;

    // W3 A-frags (g3-folded), persistent (MFMA A-operand)
    bf16x8 A3[2][2];
    #pragma unroll
    for (int mt = 0; mt < 2; ++mt) {
        int h = mt * 16 + n;
        float sc = g3[h] * BN_INV;
        #pragma unroll
        for (int ks = 0; ks < 2; ++ks) {
            const float* src = W3 + h * 64 + ks * 32 + quad * 8;
            bf16x8 v;
            #pragma unroll
            for (int j = 0; j < 8; ++j) v[j] = (bf16_t)(src[j] * sc);
            A3[mt][ks] = v;
        }
    }
    // W1 algebra (channels c = quad*8+j)
    float a8[8], V0[8], V1[8], V2[8];
    #pragma unroll
    for (int j = 0; j < 8; ++j) {
        int c = quad * 8 + j;
        float s1 = g1[c] * BN_INV;
        const float* wp = W1 + c * 10;
        a8[j] = wp[0] * s1;
        V0[j] = (wp[7] - wp[1]) * s1;
        V1[j] = (wp[8] - wp[2]) * s1;
        V2[j] = (wp[9] - wp[3]) * s1;
    }

    // uniform per-batch bases (SGPR); all per-lane offsets are 32-bit
    const bf16_t*       fb   = fbf  + (size_t)base * 32;
    const h16x4*        xzb  = xyzh + (size_t)base;
    const unsigned int* n16b = n16  + (size_t)base * 8;
    float*              outb = out  + (size_t)base * 64;
    float* bounce = sB[wv];

    // compile-time u16 extract from the 8 resident index words
    #define IDX(t) ((t) < 8 ? (((t) & 1) ? (iw0[(t) >> 1] >> 16)              \
                                         : (iw0[(t) >> 1] & 0xffffu))         \
                            : (((t) & 1) ? (iw1[((t) - 8) >> 1] >> 16)        \
                                         : (iw1[((t) - 8) >> 1] & 0xffffu)))

    for (int grp = wslot; grp < GPB; grp += WPB) {
        unsigned int nloc = (unsigned)grp * 16u;
        unsigned int t32  = nloc + (unsigned)n;   // batch-local column point

        // ALL 16 neighbor indices -> 8 resident VGPRs (one dependency, no reloads)
        uintx4 iw0 = *(const uintx4*)(n16b + (size_t)t32 * 8);
        uintx4 iw1 = *(const uintx4*)(n16b + (size_t)t32 * 8 + 4);

        h16x4 psh = xzb[t32];                     // self xyz (half4, 2 VGPR)
        float psx = (float)psh[0], psy = (float)psh[1], psz = (float)psh[2];

        float hoist[8];
        #pragma unroll
        for (int j = 0; j < 8; ++j) {
            int c = quad * 8 + j;
            float s1 = g1[c] * BN_INV;
            const float* wp = W1 + c * 10;
            hoist[j] = b1[c] + ((wp[1] + wp[4]) * psx + (wp[2] + wp[5]) * psy +
                                (wp[3] + wp[6]) * psz) * s1;
        }

        // depth-4 pipelined gather: prologue issues j0..j3
        bf16x8 fj[4]; h16x4 pn[4];
        #pragma unroll
        for (int s = 0; s < 4; ++s) {
            unsigned int j0 = IDX(s);
            fj[s] = *(const bf16x8*)(fb + j0 * 32u + quad * 8u);
            pn[s] = xzb[j0];
        }

        f32x4 mx0 = {-3.0e38f, -3.0e38f, -3.0e38f, -3.0e38f};
        f32x4 mx1 = {-3.0e38f, -3.0e38f, -3.0e38f, -3.0e38f};

        #pragma unroll
        for (int k = 0; k < 16; ++k) {
            int s = k & 3;
            h16x4 p = pn[s];
            bf16x8 Bj = fj[s];
            float pnx = (float)p[0], pny = (float)p[1], pnz = (float)p[2];

            float rx = psx - pnx, ry = psy - pny, rz = psz - pnz;
            float dist = __builtin_amdgcn_sqrtf(rx * rx + ry * ry + rz * rz);

            bf16x8 Bx;
            #pragma unroll
            for (int c = 0; c < 8; ++c) {
                float v = fmaf(a8[c], dist, hoist[c]);
                v = fmaf(V0[c], pnx, v);
                v = fmaf(V1[c], pny, v);
                v = fmaf(V2[c], pnz, v);
                Bx[c] = (bf16_t)fmaxf(v, 0.f);
            }

            f32x4 ac0 = {0,0,0,0}, ac1 = {0,0,0,0};
            ac0 = MFMA16(A3[0][0], Bj, ac0);
            ac0 = MFMA16(A3[0][1], Bx, ac0);
            ac1 = MFMA16(A3[1][0], Bj, ac1);
            ac1 = MFMA16(A3[1][1], Bx, ac1);
            #pragma unroll
            for (int r = 0; r < 4; ++r) {
                mx0[r] = fmaxf(mx0[r], ac0[r]);
                mx1[r] = fmaxf(mx1[r], ac1[r]);
            }

            if (k + 4 < 16) {
                unsigned int jn = IDX(k + 4);     // compile-time word select
                fj[s] = *(const bf16x8*)(fb + jn * 32u + quad * 8u);
                pn[s] = xzb[jn];
            }
        }

        // epilogue: bias+ReLU on max, bounce to B-layout, W4 MFMA, store
        f32x4 bz0 = *(const f32x4*)&sb34[quad * 4];
        f32x4 bz1 = *(const f32x4*)&sb34[16 + quad * 4];
        #pragma unroll
        for (int r = 0; r < 4; ++r) {
            bounce[(quad * 4 + r) * 18 + n]      = fmaxf(mx0[r] + bz0[r], 0.f);
            bounce[(16 + quad * 4 + r) * 18 + n] = fmaxf(mx1[r] + bz1[r], 0.f);
        }
        asm volatile("s_waitcnt lgkmcnt(0)" ::: "memory");
        bf16x8 Bm;
        #pragma unroll
        for (int jj = 0; jj < 8; ++jj)
            Bm[jj] = (bf16_t)bounce[(quad * 8 + jj) * 18 + n];

        bf16x8 Bs = *(const bf16x8*)(fb + t32 * 32u + quad * 8u);  // f_self

        #pragma unroll
        for (int mt = 0; mt < 4; ++mt) {
            bf16x8 A40 = *(const bf16x8*)(sW4 + ((size_t)(mt * 2 + 0) * 64 + lane) * 8);
            bf16x8 A41 = *(const bf16x8*)(sW4 + ((size_t)(mt * 2 + 1) * 64 + lane) * 8);
            f32x4 b4q = *(const f32x4*)&sb34[32 + mt * 16 + quad * 4];
            f32x4 acc = {0,0,0,0};
            acc = MFMA16(A40, Bm, acc);
            acc = MFMA16(A41, Bs, acc);
            #pragma unroll
            for (int r = 0; r < 4; ++r) {
                unsigned int o = mt * 16 + quad * 4 + r;
                float res = fmaxf(acc[r] + b4q[r], 0.f);
                __builtin_nontemporal_store(res, outb + o * (unsigned)N + t32);
            }
        }
        asm volatile("s_waitcnt lgkmcnt(0)" ::: "memory");  // drain before next group's bounce
    }
    #undef IDX
}

// ---------------------------------------------------------------------------
extern "C" void kernel_launch(void* const* d_in, const int* in_sizes, int n_in,
                              void* d_out, int out_size, void* d_ws, size_t ws_size,
                              hipStream_t stream) {
    const float* feature = (const float*)d_in[0];
    const float* xyz     = (const float*)d_in[1];
    const int*   nidx    = (const int*)  d_in[2];
    const float* W1      = (const float*)d_in[3];
    const float* W2      = (const float*)d_in[4];
    const float* W3      = (const float*)d_in[5];
    const float* W4      = (const float*)d_in[6];
    const float* g1 = (const float*)d_in[7];
    const float* b1 = (const float*)d_in[8];
    const float* g2 = (const float*)d_in[9];
    const float* b2 = (const float*)d_in[10];
    const float* g3 = (const float*)d_in[11];
    const float* b3 = (const float*)d_in[12];
    const float* g4 = (const float*)d_in[13];
    const float* b4 = (const float*)d_in[14];
    float* out = (float*)d_out;

    const int B = 4;
    const int N = in_sizes[1] / (B * 3);
    const int total = B * N;                      // 163840

    // workspace: fbf 10.49MB | xyzh 1.31MB | n16 5.24MB  (17.0MB total)
    bf16_t* fbf = (bf16_t*)d_ws;
    h16x4*  xyzh = (h16x4*)((char*)d_ws + (size_t)total * 64);
    unsigned int* n16 = (unsigned int*)((char*)d_ws + (size_t)total * 64
                                        + (size_t)total * 8);

    const int nw1 = total / 64;
    const int blk1 = (nw1 + 3) / 4;
    // k2: 1280 blocks = 256 CUs x 5 resident (valid iff VGPR <= 102 -> 5
    // waves/SIMD; this rev sheds pn/ps/offset registers to get there).
    // Divisible by 8 for the XCD decode; exactly 2 groups per wave.
    const int blk2 = 1280;

    rfa_k1<<<blk1, 256, 0, stream>>>(feature, xyz, nidx, W2, g2, b2,
                                     fbf, xyzh, n16, N, nw1);
    rfa_k2<<<blk2, 256, 0, stream>>>(fbf, xyzh, n16, W1, g1, b1, W3, g3, b3,
                                     W4, g4, b4, out, N);
}